// Round 5
// baseline (325.769 us; speedup 1.0000x reference)
//
#include <hip/hip_runtime.h>
#include <hip/hip_bf16.h>
#include <stdint.h>

#define NB 32
#define NS 2048
#define ND 1024
#define NA 1024
#define MASK_NEG 1e30f

#define BM 256
#define BN 256
#define BK 64
#define TT_TOTAL 64  // 4 a-tiles x 16 K-tiles

typedef __attribute__((ext_vector_type(4))) float f32x4;
typedef __attribute__((ext_vector_type(8))) __bf16 bf16x8;

__device__ __forceinline__ void glds16(const void* g, void* l) {
  __builtin_amdgcn_global_load_lds(
      (const __attribute__((address_space(1))) uint32_t*)g,
      (__attribute__((address_space(3))) uint32_t*)(uintptr_t)l, 16, 0, 0);
}

// ---------------- fp32 -> bf16 bulk convert ----------------
__global__ __launch_bounds__(256) void cvt_bf16(const float* __restrict__ in,
                                                __bf16* __restrict__ out, int n8) {
  long i = blockIdx.x * 256 + threadIdx.x;
  const long stride = (long)gridDim.x * 256;
  for (; i < n8; i += stride) {
    f32x4 a = ((const f32x4*)in)[2 * i];
    f32x4 b = ((const f32x4*)in)[2 * i + 1];
    bf16x8 o;
#pragma unroll
    for (int j = 0; j < 4; ++j) { o[j] = (__bf16)a[j]; o[4 + j] = (__bf16)b[j]; }
    ((bf16x8*)out)[i] = o;
  }
}

// ---------------- w1q[b,a] = query[b,:] . W1[a,:]  (fp32) ----------------
__global__ __launch_bounds__(256) void w1q_kernel(const float* __restrict__ q,
                                                  const float* __restrict__ W1,
                                                  float* __restrict__ w1q) {
  const int b = blockIdx.x;
  const int a0 = blockIdx.y * 64;
  const int t = threadIdx.x;
  const int al = t >> 2;
  const int part = t & 3;
  const float* wrow = W1 + (size_t)(a0 + al) * ND + part * 256;
  const float* qrow = q + (size_t)b * ND + part * 256;
  float sum = 0.f;
#pragma unroll 8
  for (int i = 0; i < 256; i += 4) {
    float4 w = *reinterpret_cast<const float4*>(wrow + i);
    float4 x = *reinterpret_cast<const float4*>(qrow + i);
    sum += w.x * x.x + w.y * x.y + w.z * x.z + w.w * x.w;
  }
  __shared__ float red[256];
  red[t] = sum;
  __syncthreads();
  if (t < 64) {
    w1q[(size_t)b * NA + a0 + t] = red[t * 4] + red[t * 4 + 1] + red[t * 4 + 2] + red[t * 4 + 3];
  }
}

// ---------------- fused scores GEMM: 8-slot A-ring + reg-B, counted vmcnt ----------------
// A (keys) LDS: ring of 8 half-tile slots (128 rows x 64 k bf16 = 16 KB each).
// Half-tile (tau,h) -> slot (2*tau+h)&7; staged during window tau-2, read during
// window tau, restaged during window tau+2 (>=5 barriers apart). XOR swizzle:
// stored_slot16 = col16 ^ (row&7); glds source address carries the inverse (R2-verified).
// B (W2) never touches LDS: each wave loads its 8 MFMA B-fragments (16B contiguous
// k-slices, L2-resident) into registers one K-tile ahead; compiler auto-waitcnts them.
// Checkpoint at window end: vmcnt(12) leaves A(tau+2) stagings (4) + B(tau+1) (8)
// in flight -- never drains to 0 in the main loop (T4).
__global__ __launch_bounds__(512, 1) void score_gemm8(
    const __bf16* __restrict__ keysb, const __bf16* __restrict__ W2b,
    const float* __restrict__ w1q, const float* __restrict__ vvec,
    float* __restrict__ scores) {
  __shared__ __bf16 ldsA[8 * 8192];   // 128 KB ring
  __shared__ float sm_w1q[NA];        // 4 KB
  __shared__ float sm_v[NA];          // 4 KB
  __shared__ float sm_part[4][BM];    // 4 KB

  const int t = threadIdx.x;
  const int bs0 = blockIdx.x * BM;
  const int b = bs0 >> 11;
  const int lane = t & 63;
  const int wid = t >> 6;
  const int wr = wid >> 2;   // 0..1: 128-row half of output tile
  const int wc = wid & 3;    // 0..3: 64-col quarter
  const int lrow = lane & 15;
  const int ko = lane >> 4;

  for (int i = t; i < NA; i += 512) {
    sm_w1q[i] = w1q[(size_t)b * NA + i];
    sm_v[i] = vvec[i];
  }
  for (int i = t; i < 4 * BM; i += 512) ((float*)sm_part)[i] = 0.f;
  __syncthreads();

  // staging lane geometry (R2-verified involution): chunk = 1KB = 8 rows;
  // this thread loads chunk wid and wid+8 of each 16 KB half-tile.
  const int srow = lane >> 3;
  const int scol = (lane & 7) ^ srow;
  const size_t aoff0 = (size_t)(bs0 + wid * 8 + srow) * ND + scol * 8;
  const size_t aoff1 = (size_t)(bs0 + (wid + 8) * 8 + srow) * ND + scol * 8;
  const int c0_ = wid * 1024;
  const int c1_ = (wid + 8) * 1024;

  // fragment read slots (pre-swizzled)
  const int sl0 = ko ^ (lrow & 7);
  const int sl1 = (4 + ko) ^ (lrow & 7);

  f32x4 acc[8][4];
#pragma unroll
  for (int mi = 0; mi < 8; ++mi)
#pragma unroll
    for (int ni = 0; ni < 4; ++ni) acc[mi][ni] = f32x4{0.f, 0.f, 0.f, 0.f};

  bf16x8 af[4][2];
  bf16x8 bE[4][2], bO[4][2];

#define STAGE_A(TT, H)                                                          \
  do {                                                                          \
    if ((TT) < TT_TOTAL) {                                                      \
      const int slot_ = (2 * (TT) + (H)) & 7;                                   \
      const size_t go_ = (size_t)(H) * 128 * ND + (size_t)(((TT) & 15) * BK);   \
      glds16(keysb + aoff0 + go_, (char*)ldsA + (slot_ << 14) + c0_);           \
      glds16(keysb + aoff1 + go_, (char*)ldsA + (slot_ << 14) + c1_);           \
    }                                                                           \
  } while (0)

#define LOAD_BFRAGS(DST, TT)                                                    \
  do {                                                                          \
    const int a0_ = ((TT) >> 4) * BN;                                           \
    const int k0_ = ((TT) & 15) * BK;                                           \
    _Pragma("unroll") for (int ni = 0; ni < 4; ++ni)                            \
        _Pragma("unroll") for (int kk = 0; kk < 2; ++kk)                        \
            DST[ni][kk] = *reinterpret_cast<const bf16x8*>(                     \
                W2b + (size_t)(a0_ + wc * 64 + ni * 16 + lrow) * ND + k0_ +     \
                kk * 32 + ko * 8);                                              \
  } while (0)

#define READ_AF(TAU, MIH)                                                       \
  do {                                                                          \
    const char* base_ = (const char*)ldsA + (((2 * (TAU) + wr) & 7) << 14);     \
    _Pragma("unroll") for (int mi = 0; mi < 4; ++mi) {                          \
      const int rb_ = (((MIH)*4 + mi) * 16 + lrow) * 128;                       \
      af[mi][0] = *reinterpret_cast<const bf16x8*>(base_ + rb_ + sl0 * 16);     \
      af[mi][1] = *reinterpret_cast<const bf16x8*>(base_ + rb_ + sl1 * 16);     \
    }                                                                           \
  } while (0)

#define MFMAQ(MIH, NIH, CUR)                                                    \
  _Pragma("unroll") for (int mi = 0; mi < 4; ++mi)                              \
      _Pragma("unroll") for (int nq = 0; nq < 2; ++nq) {                        \
    acc[(MIH)*4 + mi][(NIH)*2 + nq] = __builtin_amdgcn_mfma_f32_16x16x32_bf16(  \
        af[mi][0], CUR[(NIH)*2 + nq][0], acc[(MIH)*4 + mi][(NIH)*2 + nq], 0, 0, 0); \
    acc[(MIH)*4 + mi][(NIH)*2 + nq] = __builtin_amdgcn_mfma_f32_16x16x32_bf16(  \
        af[mi][1], CUR[(NIH)*2 + nq][1], acc[(MIH)*4 + mi][(NIH)*2 + nq], 0, 0, 0); \
  }

#define SETP1 __builtin_amdgcn_s_setprio(1)
#define SETP0 __builtin_amdgcn_s_setprio(0)
#define BAR __builtin_amdgcn_s_barrier()

#define WINDOW(TAU, CUR, NXT)                                                   \
  do {                                                                          \
    /* wph1: B-frags for next tile, stage A(tau+2,h0), read af-lo, Q(lo,lo) */  \
    if ((TAU) + 1 < TT_TOTAL) LOAD_BFRAGS(NXT, (TAU) + 1);                      \
    STAGE_A((TAU) + 2, 0);                                                      \
    READ_AF(TAU, 0);                                                            \
    SETP1; MFMAQ(0, 0, CUR); SETP0; BAR;                                        \
    /* wph2: Q(lo,hi) */                                                        \
    SETP1; MFMAQ(0, 1, CUR); SETP0; BAR;                                        \
    /* wph3: stage A(tau+2,h1), read af-hi, Q(hi,lo) */                         \
    STAGE_A((TAU) + 2, 1);                                                      \
    READ_AF(TAU, 1);                                                            \
    SETP1; MFMAQ(1, 0, CUR); SETP0; BAR;                                        \
    /* wph4: Q(hi,hi), counted-vmcnt checkpoint */                              \
    SETP1; MFMAQ(1, 1, CUR); SETP0;                                             \
    if ((TAU) < TT_TOTAL - 2) {                                                 \
      asm volatile("s_waitcnt vmcnt(12)" ::: "memory");                         \
    } else {                                                                    \
      asm volatile("s_waitcnt vmcnt(8)" ::: "memory");                          \
    }                                                                           \
    BAR;                                                                        \
  } while (0)

#define EPILOGUE(ATILE)                                                         \
  do {                                                                          \
    const int a0e_ = (ATILE)*BN;                                                \
    float w1v[4], vv[4];                                                        \
    _Pragma("unroll") for (int ni = 0; ni < 4; ++ni) {                          \
      const int a_ = a0e_ + wc * 64 + ni * 16 + lrow;                           \
      w1v[ni] = sm_w1q[a_];                                                     \
      vv[ni] = sm_v[a_];                                                        \
    }                                                                           \
    _Pragma("unroll") for (int mi = 0; mi < 8; ++mi)                            \
        _Pragma("unroll") for (int r = 0; r < 4; ++r) {                         \
      float p = 0.f;                                                            \
      _Pragma("unroll") for (int ni = 0; ni < 4; ++ni) {                        \
        const float x = acc[mi][ni][r] + w1v[ni];                               \
        const float e = __expf(2.f * x);                                        \
        p += (1.f - 2.f * __builtin_amdgcn_rcpf(e + 1.f)) * vv[ni];             \
      }                                                                         \
      p += __shfl_xor(p, 1);                                                    \
      p += __shfl_xor(p, 2);                                                    \
      p += __shfl_xor(p, 4);                                                    \
      p += __shfl_xor(p, 8);                                                    \
      if (lrow == 0) sm_part[wc][wr * 128 + mi * 16 + ko * 4 + r] += p;         \
    }                                                                           \
    _Pragma("unroll") for (int mi = 0; mi < 8; ++mi)                            \
        _Pragma("unroll") for (int ni = 0; ni < 4; ++ni)                        \
            acc[mi][ni] = f32x4{0.f, 0.f, 0.f, 0.f};                            \
  } while (0)

  // ---- prologue: A(0),A(1) staged; B(0) into bE; wait A(0) only ----
  STAGE_A(0, 0);
  STAGE_A(0, 1);
  STAGE_A(1, 0);
  STAGE_A(1, 1);
  LOAD_BFRAGS(bE, 0);
  asm volatile("s_waitcnt vmcnt(12)" ::: "memory");
  BAR;

  for (int tau = 0; tau < TT_TOTAL; tau += 2) {
    WINDOW(tau, bE, bO);
    WINDOW(tau + 1, bO, bE);
    if (((tau + 1) & 15) == 15) EPILOGUE((tau + 1) >> 4);
  }

  __syncthreads();
  if (t < BM)
    scores[bs0 + t] = sm_part[0][t] + sm_part[1][t] + sm_part[2][t] + sm_part[3][t];

#undef STAGE_A
#undef LOAD_BFRAGS
#undef READ_AF
#undef MFMAQ
#undef WINDOW
#undef EPILOGUE
#undef SETP1
#undef SETP0
#undef BAR
}

// ---------------- masked softmax ----------------
__global__ __launch_bounds__(256) void softmax_kernel(const float* __restrict__ scores,
                                                      const int* __restrict__ mask,
                                                      float* __restrict__ out) {
  const int b = blockIdx.x;
  const int t = threadIdx.x;
  float sc[8];
  float mx = -3.4e38f;
#pragma unroll
  for (int j = 0; j < 8; ++j) {
    int i = t + j * 256;
    float s = scores[b * NS + i];
    if (mask[b * NS + i] == 0) s -= MASK_NEG;
    sc[j] = s;
    mx = fmaxf(mx, s);
  }
#pragma unroll
  for (int off = 1; off < 64; off <<= 1) mx = fmaxf(mx, __shfl_xor(mx, off));
  __shared__ float redm[4];
  __shared__ float reds[4];
  if ((t & 63) == 0) redm[t >> 6] = mx;
  __syncthreads();
  mx = fmaxf(fmaxf(redm[0], redm[1]), fmaxf(redm[2], redm[3]));
  float e[8];
  float sum = 0.f;
#pragma unroll
  for (int j = 0; j < 8; ++j) {
    e[j] = __expf(sc[j] - mx);
    sum += e[j];
  }
#pragma unroll
  for (int off = 1; off < 64; off <<= 1) sum += __shfl_xor(sum, off);
  if ((t & 63) == 0) reds[t >> 6] = sum;
  __syncthreads();
  sum = reds[0] + reds[1] + reds[2] + reds[3];
  float inv = 1.f / sum;
#pragma unroll
  for (int j = 0; j < 8; ++j) out[b * NS + t + j * 256] = e[j] * inv;
}

extern "C" void kernel_launch(void* const* d_in, const int* in_sizes, int n_in,
                              void* d_out, int out_size, void* d_ws, size_t ws_size,
                              hipStream_t stream) {
  const float* q = (const float*)d_in[0];
  const float* keysf = (const float*)d_in[1];
  const int* mask = (const int*)d_in[2];
  const float* W1 = (const float*)d_in[3];
  const float* W2f = (const float*)d_in[4];
  const float* v = (const float*)d_in[5];
  float* out = (float*)d_out;

  float* scores = (float*)d_ws;                                 // 256 KB
  float* w1q = scores + NB * NS;                                // 128 KB
  __bf16* W2b = (__bf16*)(w1q + NB * NA);                       // 2 MB
  __bf16* keysb = (__bf16*)((char*)W2b + (size_t)NA * ND * 2);  // 128 MB

  cvt_bf16<<<512, 256, 0, stream>>>(W2f, W2b, NA * ND / 8);
  cvt_bf16<<<2048, 256, 0, stream>>>(keysf, keysb, (int)((size_t)NB * NS * ND / 8));
  w1q_kernel<<<dim3(NB, NA / 64), 256, 0, stream>>>(q, W1, w1q);
  score_gemm8<<<NB * NS / BM, 512, 0, stream>>>(keysb, W2b, w1q, v, scores);
  softmax_kernel<<<NB, 256, 0, stream>>>(scores, mask, out);
}

// Round 6
// 257.726 us; speedup vs baseline: 1.2640x; 1.2640x over previous
//
#include <hip/hip_runtime.h>
#include <hip/hip_bf16.h>
#include <stdint.h>

#define NB 32
#define NS 2048
#define ND 1024
#define NA 1024
#define MASK_NEG 1e30f

#define BM 256
#define BN 256
#define BK 64
#define TT_TOTAL 64  // 4 a-tiles x 16 K-tiles

typedef __attribute__((ext_vector_type(4))) float f32x4;
typedef __attribute__((ext_vector_type(8))) __bf16 bf16x8;

__device__ __forceinline__ void glds16(const void* g, void* l) {
  __builtin_amdgcn_global_load_lds(
      (const __attribute__((address_space(1))) uint32_t*)g,
      (__attribute__((address_space(3))) uint32_t*)(uintptr_t)l, 16, 0, 0);
}

// ---------------- fp32 -> bf16 bulk convert ----------------
__global__ __launch_bounds__(256) void cvt_bf16(const float* __restrict__ in,
                                                __bf16* __restrict__ out, int n8) {
  long i = blockIdx.x * 256 + threadIdx.x;
  const long stride = (long)gridDim.x * 256;
  for (; i < n8; i += stride) {
    f32x4 a = ((const f32x4*)in)[2 * i];
    f32x4 b = ((const f32x4*)in)[2 * i + 1];
    bf16x8 o;
#pragma unroll
    for (int j = 0; j < 4; ++j) { o[j] = (__bf16)a[j]; o[4 + j] = (__bf16)b[j]; }
    ((bf16x8*)out)[i] = o;
  }
}

// ---------------- w1q[b,a] = query[b,:] . W1[a,:]  (fp32) ----------------
__global__ __launch_bounds__(256) void w1q_kernel(const float* __restrict__ q,
                                                  const float* __restrict__ W1,
                                                  float* __restrict__ w1q) {
  const int b = blockIdx.x;
  const int a0 = blockIdx.y * 64;
  const int t = threadIdx.x;
  const int al = t >> 2;
  const int part = t & 3;
  const float* wrow = W1 + (size_t)(a0 + al) * ND + part * 256;
  const float* qrow = q + (size_t)b * ND + part * 256;
  float sum = 0.f;
#pragma unroll 8
  for (int i = 0; i < 256; i += 4) {
    float4 w = *reinterpret_cast<const float4*>(wrow + i);
    float4 x = *reinterpret_cast<const float4*>(qrow + i);
    sum += w.x * x.x + w.y * x.y + w.z * x.z + w.w * x.w;
  }
  __shared__ float red[256];
  red[t] = sum;
  __syncthreads();
  if (t < 64) {
    w1q[(size_t)b * NA + a0 + t] = red[t * 4] + red[t * 4 + 1] + red[t * 4 + 2] + red[t * 4 + 3];
  }
}

// ---------------- fused scores GEMM, 4-phase, counted-latency staging ----------------
// Double-buffered 256x256x64 tile, 8 waves (2M x 4N, 128x64 per wave).
// All A-stagings for tile tt+1 issue at phase 1, all B at phase 2; the single
// vmcnt(0) at phase-4 end is then 2-3.5 phases after issue (~1300-1900 cyc)
// -> HBM latency covered, drain ~free. NO memory clobbers on waitcnt asms
// (a "memory" clobber makes the compiler insert a hidden vmcnt(0) before the
// asm, since global_load_lds writes LDS). sched_barrier(0) pins ordering.
// XOR swizzle (R2-verified, 0 conflicts): stored_slot16 = col16 ^ (row&7),
// inverse carried on the glds global source address.
__global__ __launch_bounds__(512, 1) void score_gemm8(
    const __bf16* __restrict__ keysb, const __bf16* __restrict__ W2b,
    const float* __restrict__ w1q, const float* __restrict__ vvec,
    float* __restrict__ scores) {
  __shared__ __bf16 Ab[2][BM * BK];   // 2 x 32 KB
  __shared__ __bf16 Bb[2][BN * BK];   // 2 x 32 KB
  __shared__ float sm_w1q[NA];        // 4 KB
  __shared__ float sm_v[NA];          // 4 KB
  __shared__ float sm_part[4][BM];    // 4 KB

  const int t = threadIdx.x;
  const int bs0 = blockIdx.x * BM;
  const int b = bs0 >> 11;  // / NS
  const int lane = t & 63;
  const int wid = t >> 6;
  const int wr = wid >> 2;   // 0..1: 128-row half
  const int wc = wid & 3;    // 0..3: 64-col quarter
  const int lrow = lane & 15;
  const int ko = lane >> 4;

  for (int i = t; i < NA; i += 512) {
    sm_w1q[i] = w1q[(size_t)b * NA + i];
    sm_v[i] = vvec[i];
  }
  for (int i = t; i < 4 * BM; i += 512) ((float*)sm_part)[i] = 0.f;

  // staging lane geometry (R2-verified involution): chunk = 1KB = 8 rows of
  // 128B; thread covers chunk r*8+wid, lane -> row srow, stored slot lane&7,
  // fetched logical col16 = (lane&7) ^ srow.
  const int srow = lane >> 3;
  const int scol = (lane & 7) ^ srow;
  size_t aoffg[4], boffg[4];
#pragma unroll
  for (int r = 0; r < 4; ++r) {
    const int row = (r * 8 + wid) * 8 + srow;
    aoffg[r] = (size_t)(bs0 + row) * ND + scol * 8;
    boffg[r] = (size_t)row * ND + scol * 8;
  }
  const int ldsoff = wid * 1024;

  // fragment read slots (pre-swizzled; row offsets are multiples of 8)
  const int sl0 = ko ^ (lrow & 7);
  const int sl1 = (4 + ko) ^ (lrow & 7);

  f32x4 acc[8][4];
#pragma unroll
  for (int mi = 0; mi < 8; ++mi)
#pragma unroll
    for (int ni = 0; ni < 4; ++ni) acc[mi][ni] = f32x4{0.f, 0.f, 0.f, 0.f};

#define WAITL asm volatile("s_waitcnt lgkmcnt(0)")
#define WAITV0 asm volatile("s_waitcnt vmcnt(0)")
#define SB __builtin_amdgcn_sched_barrier(0)
#define P1 __builtin_amdgcn_s_setprio(1)
#define P0 __builtin_amdgcn_s_setprio(0)
#define BAR __builtin_amdgcn_s_barrier()

  // ---- prologue: stage tile 0 into buf 0 ----
#pragma unroll
  for (int r = 0; r < 4; ++r) {
    glds16(keysb + aoffg[r], (char*)Ab[0] + ldsoff + r * 8192);
    glds16(W2b + boffg[r], (char*)Bb[0] + ldsoff + r * 8192);
  }
  __syncthreads();  // drains vmcnt + sm_w1q/sm_part init

  for (int tt = 0; tt < TT_TOTAL; ++tt) {
    const int c = tt & 1;
    const char* Ac = (const char*)Ab[c];
    const char* Bc = (const char*)Bb[c];
    char* An = (char*)Ab[c ^ 1];
    char* Bn = (char*)Bb[c ^ 1];
    const int ntt = tt + 1;
    const bool hn = ntt < TT_TOTAL;
    const size_t akoff = (size_t)((ntt & 15) * BK);
    const size_t bkoff = (size_t)((ntt >> 4) * BN) * ND + (size_t)((ntt & 15) * BK);

    bf16x8 bfr[4][2], af[4][2];

    // ======== phase 1: stage ALL A(ntt) | read bfr[0..1] + af-lo | MFMA Q(lo,0-1) ========
    if (hn) {
#pragma unroll
      for (int r = 0; r < 4; ++r)
        glds16(keysb + aoffg[r] + akoff, An + ldsoff + r * 8192);
    }
#pragma unroll
    for (int ni = 0; ni < 2; ++ni) {
      const int rb = (wc * 64 + ni * 16 + lrow) * 128;
      bfr[ni][0] = *reinterpret_cast<const bf16x8*>(Bc + rb + sl0 * 16);
      bfr[ni][1] = *reinterpret_cast<const bf16x8*>(Bc + rb + sl1 * 16);
    }
#pragma unroll
    for (int mi = 0; mi < 4; ++mi) {
      const int ra = (wr * 128 + mi * 16 + lrow) * 128;
      af[mi][0] = *reinterpret_cast<const bf16x8*>(Ac + ra + sl0 * 16);
      af[mi][1] = *reinterpret_cast<const bf16x8*>(Ac + ra + sl1 * 16);
    }
    BAR;
    WAITL;
    SB;
    P1;
#pragma unroll
    for (int mi = 0; mi < 4; ++mi)
#pragma unroll
      for (int ni = 0; ni < 2; ++ni) {
        acc[mi][ni] = __builtin_amdgcn_mfma_f32_16x16x32_bf16(af[mi][0], bfr[ni][0], acc[mi][ni], 0, 0, 0);
        acc[mi][ni] = __builtin_amdgcn_mfma_f32_16x16x32_bf16(af[mi][1], bfr[ni][1], acc[mi][ni], 0, 0, 0);
      }
    P0;
    BAR;

    // ======== phase 2: stage ALL B(ntt) | read bfr[2..3] | MFMA Q(lo,2-3) ========
    if (hn) {
#pragma unroll
      for (int r = 0; r < 4; ++r)
        glds16(W2b + boffg[r] + bkoff, Bn + ldsoff + r * 8192);
    }
#pragma unroll
    for (int ni = 2; ni < 4; ++ni) {
      const int rb = (wc * 64 + ni * 16 + lrow) * 128;
      bfr[ni][0] = *reinterpret_cast<const bf16x8*>(Bc + rb + sl0 * 16);
      bfr[ni][1] = *reinterpret_cast<const bf16x8*>(Bc + rb + sl1 * 16);
    }
    BAR;
    WAITL;
    SB;
    P1;
#pragma unroll
    for (int mi = 0; mi < 4; ++mi)
#pragma unroll
      for (int ni = 2; ni < 4; ++ni) {
        acc[mi][ni] = __builtin_amdgcn_mfma_f32_16x16x32_bf16(af[mi][0], bfr[ni][0], acc[mi][ni], 0, 0, 0);
        acc[mi][ni] = __builtin_amdgcn_mfma_f32_16x16x32_bf16(af[mi][1], bfr[ni][1], acc[mi][ni], 0, 0, 0);
      }
    P0;
    BAR;

    // ======== phase 3: read af-hi | MFMA Q(hi,0-1) ========
#pragma unroll
    for (int mi = 0; mi < 4; ++mi) {
      const int ra = (wr * 128 + 64 + mi * 16 + lrow) * 128;
      af[mi][0] = *reinterpret_cast<const bf16x8*>(Ac + ra + sl0 * 16);
      af[mi][1] = *reinterpret_cast<const bf16x8*>(Ac + ra + sl1 * 16);
    }
    BAR;
    WAITL;
    SB;
    P1;
#pragma unroll
    for (int mi = 0; mi < 4; ++mi)
#pragma unroll
      for (int ni = 0; ni < 2; ++ni) {
        acc[4 + mi][ni] = __builtin_amdgcn_mfma_f32_16x16x32_bf16(af[mi][0], bfr[ni][0], acc[4 + mi][ni], 0, 0, 0);
        acc[4 + mi][ni] = __builtin_amdgcn_mfma_f32_16x16x32_bf16(af[mi][1], bfr[ni][1], acc[4 + mi][ni], 0, 0, 0);
      }
    P0;
    BAR;

    // ======== phase 4: MFMA Q(hi,2-3) | vmcnt(0) (covered: issued 2-3.5 phases ago) ========
    P1;
#pragma unroll
    for (int mi = 0; mi < 4; ++mi)
#pragma unroll
      for (int ni = 2; ni < 4; ++ni) {
        acc[4 + mi][ni] = __builtin_amdgcn_mfma_f32_16x16x32_bf16(af[mi][0], bfr[ni][0], acc[4 + mi][ni], 0, 0, 0);
        acc[4 + mi][ni] = __builtin_amdgcn_mfma_f32_16x16x32_bf16(af[mi][1], bfr[ni][1], acc[4 + mi][ni], 0, 0, 0);
      }
    P0;
    WAITV0;
    SB;
    BAR;

    // ======== per-a-tile epilogue: tanh + v-weight -> sm_part ========
    if ((tt & 15) == 15) {
      const int a0 = (tt >> 4) * BN;
      float w1v[4], vv[4];
#pragma unroll
      for (int ni = 0; ni < 4; ++ni) {
        const int a = a0 + wc * 64 + ni * 16 + lrow;
        w1v[ni] = sm_w1q[a];
        vv[ni] = sm_v[a];
      }
#pragma unroll
      for (int mi = 0; mi < 8; ++mi)
#pragma unroll
        for (int r = 0; r < 4; ++r) {
          float p = 0.f;
#pragma unroll
          for (int ni = 0; ni < 4; ++ni) {
            const float x = acc[mi][ni][r] + w1v[ni];
            const float e = __expf(2.f * x);
            p += (1.f - 2.f * __builtin_amdgcn_rcpf(e + 1.f)) * vv[ni];
          }
          p += __shfl_xor(p, 1);
          p += __shfl_xor(p, 2);
          p += __shfl_xor(p, 4);
          p += __shfl_xor(p, 8);
          if (lrow == 0) sm_part[wc][wr * 128 + mi * 16 + ko * 4 + r] += p;
        }
#pragma unroll
      for (int mi = 0; mi < 8; ++mi)
#pragma unroll
        for (int ni = 0; ni < 4; ++ni) acc[mi][ni] = f32x4{0.f, 0.f, 0.f, 0.f};
    }
  }

  __syncthreads();
  if (t < BM)
    scores[bs0 + t] = sm_part[0][t] + sm_part[1][t] + sm_part[2][t] + sm_part[3][t];

#undef WAITL
#undef WAITV0
#undef SB
#undef P1
#undef P0
#undef BAR
}

// ---------------- masked softmax ----------------
__global__ __launch_bounds__(256) void softmax_kernel(const float* __restrict__ scores,
                                                      const int* __restrict__ mask,
                                                      float* __restrict__ out) {
  const int b = blockIdx.x;
  const int t = threadIdx.x;
  float sc[8];
  float mx = -3.4e38f;
#pragma unroll
  for (int j = 0; j < 8; ++j) {
    int i = t + j * 256;
    float s = scores[b * NS + i];
    if (mask[b * NS + i] == 0) s -= MASK_NEG;
    sc[j] = s;
    mx = fmaxf(mx, s);
  }
#pragma unroll
  for (int off = 1; off < 64; off <<= 1) mx = fmaxf(mx, __shfl_xor(mx, off));
  __shared__ float redm[4];
  __shared__ float reds[4];
  if ((t & 63) == 0) redm[t >> 6] = mx;
  __syncthreads();
  mx = fmaxf(fmaxf(redm[0], redm[1]), fmaxf(redm[2], redm[3]));
  float e[8];
  float sum = 0.f;
#pragma unroll
  for (int j = 0; j < 8; ++j) {
    e[j] = __expf(sc[j] - mx);
    sum += e[j];
  }
#pragma unroll
  for (int off = 1; off < 64; off <<= 1) sum += __shfl_xor(sum, off);
  if ((t & 63) == 0) reds[t >> 6] = sum;
  __syncthreads();
  sum = reds[0] + reds[1] + reds[2] + reds[3];
  float inv = 1.f / sum;
#pragma unroll
  for (int j = 0; j < 8; ++j) out[b * NS + t + j * 256] = e[j] * inv;
}

extern "C" void kernel_launch(void* const* d_in, const int* in_sizes, int n_in,
                              void* d_out, int out_size, void* d_ws, size_t ws_size,
                              hipStream_t stream) {
  const float* q = (const float*)d_in[0];
  const float* keysf = (const float*)d_in[1];
  const int* mask = (const int*)d_in[2];
  const float* W1 = (const float*)d_in[3];
  const float* W2f = (const float*)d_in[4];
  const float* v = (const float*)d_in[5];
  float* out = (float*)d_out;

  float* scores = (float*)d_ws;                                 // 256 KB
  float* w1q = scores + NB * NS;                                // 128 KB
  __bf16* W2b = (__bf16*)(w1q + NB * NA);                       // 2 MB
  __bf16* keysb = (__bf16*)((char*)W2b + (size_t)NA * ND * 2);  // 128 MB

  cvt_bf16<<<512, 256, 0, stream>>>(W2f, W2b, NA * ND / 8);
  cvt_bf16<<<2048, 256, 0, stream>>>(keysf, keysb, (int)((size_t)NB * NS * ND / 8));
  w1q_kernel<<<dim3(NB, NA / 64), 256, 0, stream>>>(q, W1, w1q);
  score_gemm8<<<NB * NS / BM, 512, 0, stream>>>(keysb, W2b, w1q, v, scores);
  softmax_kernel<<<NB, 256, 0, stream>>>(scores, mask, out);
}

// Round 8
// 253.220 us; speedup vs baseline: 1.2865x; 1.0178x over previous
//
#include <hip/hip_runtime.h>
#include <hip/hip_bf16.h>
#include <stdint.h>

#define NB 32
#define NS 2048
#define ND 1024
#define NA 1024
#define MASK_NEG 1e30f

#define BM 256
#define BN 256
#define BK 64
#define NTILES 64  // 4 a-tiles x 16 K-tiles

typedef __attribute__((ext_vector_type(4))) float f32x4;
typedef __attribute__((ext_vector_type(8))) __bf16 bf16x8;

__device__ __forceinline__ void glds16(const void* g, void* l) {
  __builtin_amdgcn_global_load_lds(
      (const __attribute__((address_space(1))) uint32_t*)g,
      (__attribute__((address_space(3))) uint32_t*)(uintptr_t)l, 16, 0, 0);
}

// ---------------- fp32 -> bf16 bulk convert ----------------
__global__ __launch_bounds__(256) void cvt_bf16(const float* __restrict__ in,
                                                __bf16* __restrict__ out, int n8) {
  long i = blockIdx.x * 256 + threadIdx.x;
  const long stride = (long)gridDim.x * 256;
  for (; i < n8; i += stride) {
    f32x4 a = ((const f32x4*)in)[2 * i];
    f32x4 b = ((const f32x4*)in)[2 * i + 1];
    bf16x8 o;
#pragma unroll
    for (int j = 0; j < 4; ++j) { o[j] = (__bf16)a[j]; o[4 + j] = (__bf16)b[j]; }
    ((bf16x8*)out)[i] = o;
  }
}

// ---------------- w1q[b,a] = query[b,:] . W1[a,:]  (fp32) ----------------
__global__ __launch_bounds__(256) void w1q_kernel(const float* __restrict__ q,
                                                  const float* __restrict__ W1,
                                                  float* __restrict__ w1q) {
  const int b = blockIdx.x;
  const int a0 = blockIdx.y * 64;
  const int t = threadIdx.x;
  const int al = t >> 2;
  const int part = t & 3;
  const float* wrow = W1 + (size_t)(a0 + al) * ND + part * 256;
  const float* qrow = q + (size_t)b * ND + part * 256;
  float sum = 0.f;
#pragma unroll 8
  for (int i = 0; i < 256; i += 4) {
    float4 w = *reinterpret_cast<const float4*>(wrow + i);
    float4 x = *reinterpret_cast<const float4*>(qrow + i);
    sum += w.x * x.x + w.y * x.y + w.z * x.z + w.w * x.w;
  }
  __shared__ float red[256];
  red[t] = sum;
  __syncthreads();
  if (t < 64) {
    w1q[(size_t)b * NA + a0 + t] = red[t * 4] + red[t * 4 + 1] + red[t * 4 + 2] + red[t * 4 + 3];
  }
}

// ---------------- fused scores GEMM: m201-style 8-phase, staggered halves ----------------
// 2 K-tiles per iteration, 8 phases. LDS per operand: 2 tile-slots (slot=tile&1)
// x 2 row-halves of 128x64 bf16 (16 KB each). One half-tile staged per phase,
// into the slot-half freed in the previous phase:
//   ph1:A(t1,h1) ph2:B(t1,h0) ph3:B(t1,h1) ph4:A(t0+2,h0)
//   ph5:A(t0+2,h1) ph6:B(t0+2,h0) ph7:B(t0+2,h1) ph8:A(t1+2,h0)
// Counted vmcnt(2) at ph4/ph8 only (leaves the newest phase's 2 glds in
// flight); every half-tile's covering wait is followed by >=1 barrier before
// any read. A (HBM) gets 3-4 phases of cover, B (L2) 1-2. Tail iter drains.
// XOR swizzle (R2-verified, 0 conflicts): stored_slot16 = col16 ^ (row&7),
// inverse carried on the glds global source address.
__global__ __launch_bounds__(512, 1) void score_gemm8(
    const __bf16* __restrict__ keysb, const __bf16* __restrict__ W2b,
    const float* __restrict__ w1q, const float* __restrict__ vvec,
    float* __restrict__ scores) {
  __shared__ __bf16 ldsA[4][128 * BK];  // [slot*2+half][...] 64 KB
  __shared__ __bf16 ldsB[4][128 * BK];  // 64 KB
  __shared__ float sm_w1q[NA];          // 4 KB
  __shared__ float sm_v[NA];            // 4 KB
  __shared__ float sm_part[4][BM];      // 4 KB

  const int t = threadIdx.x;
  const int bs0 = blockIdx.x * BM;
  const int b = bs0 >> 11;  // / NS
  const int lane = t & 63;
  const int wid = t >> 6;
  const int wr = wid >> 2;   // 0..1: 128-row half of output
  const int wc = wid & 3;    // 0..3: 64-col quarter; B-half = wc>>1
  const int lrow = lane & 15;
  const int ko = lane >> 4;

  for (int i = t; i < NA; i += 512) {
    sm_w1q[i] = w1q[(size_t)b * NA + i];
    sm_v[i] = vvec[i];
  }
  for (int i = t; i < 4 * BM; i += 512) ((float*)sm_part)[i] = 0.f;

  // staging lane geometry (R2-verified involution): 1 glds = 1 KB = 8 rows of
  // 128 B; this thread stages rows wid*16+j*8+srow (j=0,1) of each half-tile.
  const int srow = lane >> 3;
  const int scol = (lane & 7) ^ srow;
  const size_t aoffT = (size_t)(bs0 + wid * 16 + srow) * ND + scol * 8;
  const size_t boffT = (size_t)(wid * 16 + srow) * ND + scol * 8;

  // fragment read slots (pre-swizzled; row offsets are multiples of 8)
  const int sl0 = ko ^ (lrow & 7);
  const int sl1 = (4 + ko) ^ (lrow & 7);

#define STAGE_A(T, H)                                                           \
  do {                                                                          \
    if ((T) < NTILES) {                                                         \
      char* d_ = (char*)ldsA + (((((T)&1) << 1) + (H)) << 14) + wid * 2048;     \
      const size_t g_ = aoffT + (size_t)((H)*128) * ND + (size_t)(((T)&15) * BK); \
      glds16(keysb + g_, d_);                                                   \
      glds16(keysb + g_ + (size_t)8 * ND, d_ + 1024);                           \
    }                                                                           \
  } while (0)

#define STAGE_B(T, H)                                                           \
  do {                                                                          \
    if ((T) < NTILES) {                                                         \
      char* d_ = (char*)ldsB + (((((T)&1) << 1) + (H)) << 14) + wid * 2048;     \
      const size_t g_ = boffT + (size_t)(((T) >> 4) * 256 + (H)*128) * ND +     \
                        (size_t)(((T)&15) * BK);                                \
      glds16(W2b + g_, d_);                                                     \
      glds16(W2b + g_ + (size_t)8 * ND, d_ + 1024);                             \
    }                                                                           \
  } while (0)

#define SB __builtin_amdgcn_sched_barrier(0)
#define P1 __builtin_amdgcn_s_setprio(1)
#define P0 __builtin_amdgcn_s_setprio(0)
#define BAR __builtin_amdgcn_s_barrier()

  // PHASE: reads (af only on N_==0 phases; reused on N_==1) + 1 half-tile
  // stage -> BAR -> lgkm(0) -> 16 MFMA -> [counted vmcnt] -> BAR.
#define PHASE(TL, M_, N_, STAGE_STMT, WM)                                       \
  do {                                                                          \
    if ((N_) == 0) {                                                            \
      const char* Ab_ = (const char*)ldsA + (((((TL)&1) << 1) | wr) << 14);     \
      _Pragma("unroll") for (int mi = 0; mi < 4; ++mi) {                        \
        const int ra_ = (((M_)*4 + mi) * 16 + lrow) * 128;                      \
        af[mi][0] = *reinterpret_cast<const bf16x8*>(Ab_ + ra_ + sl0 * 16);     \
        af[mi][1] = *reinterpret_cast<const bf16x8*>(Ab_ + ra_ + sl1 * 16);     \
      }                                                                         \
    }                                                                           \
    {                                                                           \
      const char* Bb_ = (const char*)ldsB + (((((TL)&1) << 1) | (wc >> 1)) << 14); \
      _Pragma("unroll") for (int nq = 0; nq < 2; ++nq) {                        \
        const int rb_ = (((wc & 1) * 4 + (N_)*2 + nq) * 16 + lrow) * 128;       \
        bfr[nq][0] = *reinterpret_cast<const bf16x8*>(Bb_ + rb_ + sl0 * 16);    \
        bfr[nq][1] = *reinterpret_cast<const bf16x8*>(Bb_ + rb_ + sl1 * 16);    \
      }                                                                         \
    }                                                                           \
    STAGE_STMT;                                                                 \
    BAR;                                                                        \
    asm volatile("s_waitcnt lgkmcnt(0)");                                       \
    SB;                                                                         \
    P1;                                                                         \
    _Pragma("unroll") for (int mi = 0; mi < 4; ++mi)                            \
        _Pragma("unroll") for (int nq = 0; nq < 2; ++nq) {                      \
      acc[(M_)*4 + mi][(N_)*2 + nq] = __builtin_amdgcn_mfma_f32_16x16x32_bf16(  \
          af[mi][0], bfr[nq][0], acc[(M_)*4 + mi][(N_)*2 + nq], 0, 0, 0);       \
      acc[(M_)*4 + mi][(N_)*2 + nq] = __builtin_amdgcn_mfma_f32_16x16x32_bf16(  \
          af[mi][1], bfr[nq][1], acc[(M_)*4 + mi][(N_)*2 + nq], 0, 0, 0);       \
    }                                                                           \
    P0;                                                                         \
    if (WM) {                                                                   \
      if (it != 31) { asm volatile("s_waitcnt vmcnt(2)"); }                     \
      else { asm volatile("s_waitcnt vmcnt(0)"); }                              \
      SB;                                                                       \
    }                                                                           \
    BAR;                                                                        \
  } while (0)

  f32x4 acc[8][4];
#pragma unroll
  for (int mi = 0; mi < 8; ++mi)
#pragma unroll
    for (int ni = 0; ni < 4; ++ni) acc[mi][ni] = f32x4{0.f, 0.f, 0.f, 0.f};

  bf16x8 af[4][2], bfr[2][2];

  // ---- prologue: A(0,*), B(0,*), A(1,h0); drain once ----
  STAGE_A(0, 0);
  STAGE_A(0, 1);
  STAGE_B(0, 0);
  STAGE_B(0, 1);
  STAGE_A(1, 0);
  __syncthreads();  // compiler drains vmcnt before barrier; also sm_* init

  for (int it = 0; it < 32; ++it) {
    const int t0 = 2 * it, t1 = 2 * it + 1;
    PHASE(t0, 0, 0, STAGE_A(t1, 1), 0);       // ph1
    PHASE(t0, 0, 1, STAGE_B(t1, 0), 0);       // ph2
    PHASE(t0, 1, 0, STAGE_B(t1, 1), 0);       // ph3
    PHASE(t0, 1, 1, STAGE_A(t0 + 2, 0), 1);   // ph4 + vmcnt(2)
    PHASE(t1, 0, 0, STAGE_A(t0 + 2, 1), 0);   // ph5
    PHASE(t1, 0, 1, STAGE_B(t0 + 2, 0), 0);   // ph6
    PHASE(t1, 1, 0, STAGE_B(t0 + 2, 1), 0);   // ph7
    PHASE(t1, 1, 1, STAGE_A(t1 + 2, 0), 1);   // ph8 + vmcnt(2)

    // ---- per-a-tile epilogue: tanh + v-weight -> sm_part ----
    if ((it & 7) == 7) {
      const int a0 = (it >> 3) * BN;
      float w1v[4], vv[4];
#pragma unroll
      for (int ni = 0; ni < 4; ++ni) {
        const int a = a0 + wc * 64 + ni * 16 + lrow;
        w1v[ni] = sm_w1q[a];
        vv[ni] = sm_v[a];
      }
#pragma unroll
      for (int mi = 0; mi < 8; ++mi)
#pragma unroll
        for (int r = 0; r < 4; ++r) {
          float p = 0.f;
#pragma unroll
          for (int ni = 0; ni < 4; ++ni) {
            const float x = acc[mi][ni][r] + w1v[ni];
            const float e = __expf(2.f * x);
            p += (1.f - 2.f * __builtin_amdgcn_rcpf(e + 1.f)) * vv[ni];
          }
          p += __shfl_xor(p, 1);
          p += __shfl_xor(p, 2);
          p += __shfl_xor(p, 4);
          p += __shfl_xor(p, 8);
          if (lrow == 0) sm_part[wc][wr * 128 + mi * 16 + ko * 4 + r] += p;
        }
#pragma unroll
      for (int mi = 0; mi < 8; ++mi)
#pragma unroll
        for (int ni = 0; ni < 4; ++ni) acc[mi][ni] = f32x4{0.f, 0.f, 0.f, 0.f};
    }
  }

  __syncthreads();
  if (t < BM)
    scores[bs0 + t] = sm_part[0][t] + sm_part[1][t] + sm_part[2][t] + sm_part[3][t];

#undef STAGE_A
#undef STAGE_B
#undef PHASE
#undef SB
#undef P1
#undef P0
#undef BAR
}

// ---------------- masked softmax ----------------
__global__ __launch_bounds__(256) void softmax_kernel(const float* __restrict__ scores,
                                                      const int* __restrict__ mask,
                                                      float* __restrict__ out) {
  const int b = blockIdx.x;
  const int t = threadIdx.x;
  float sc[8];
  float mx = -3.4e38f;
#pragma unroll
  for (int j = 0; j < 8; ++j) {
    int i = t + j * 256;
    float s = scores[b * NS + i];
    if (mask[b * NS + i] == 0) s -= MASK_NEG;
    sc[j] = s;
    mx = fmaxf(mx, s);
  }
#pragma unroll
  for (int off = 1; off < 64; off <<= 1) mx = fmaxf(mx, __shfl_xor(mx, off));
  __shared__ float redm[4];
  __shared__ float reds[4];
  if ((t & 63) == 0) redm[t >> 6] = mx;
  __syncthreads();
  mx = fmaxf(fmaxf(redm[0], redm[1]), fmaxf(redm[2], redm[3]));
  float e[8];
  float sum = 0.f;
#pragma unroll
  for (int j = 0; j < 8; ++j) {
    e[j] = __expf(sc[j] - mx);
    sum += e[j];
  }
#pragma unroll
  for (int off = 1; off < 64; off <<= 1) sum += __shfl_xor(sum, off);
  if ((t & 63) == 0) reds[t >> 6] = sum;
  __syncthreads();
  sum = reds[0] + reds[1] + reds[2] + reds[3];
  float inv = 1.f / sum;
#pragma unroll
  for (int j = 0; j < 8; ++j) out[b * NS + t + j * 256] = e[j] * inv;
}

extern "C" void kernel_launch(void* const* d_in, const int* in_sizes, int n_in,
                              void* d_out, int out_size, void* d_ws, size_t ws_size,
                              hipStream_t stream) {
  const float* q = (const float*)d_in[0];
  const float* keysf = (const float*)d_in[1];
  const int* mask = (const int*)d_in[2];
  const float* W1 = (const float*)d_in[3];
  const float* W2f = (const float*)d_in[4];
  const float* v = (const float*)d_in[5];
  float* out = (float*)d_out;

  float* scores = (float*)d_ws;                                 // 256 KB
  float* w1q = scores + NB * NS;                                // 128 KB
  __bf16* W2b = (__bf16*)(w1q + NB * NA);                       // 2 MB
  __bf16* keysb = (__bf16*)((char*)W2b + (size_t)NA * ND * 2);  // 128 MB

  cvt_bf16<<<512, 256, 0, stream>>>(W2f, W2b, NA * ND / 8);
  cvt_bf16<<<2048, 256, 0, stream>>>(keysf, keysb, (int)((size_t)NB * NS * ND / 8));
  w1q_kernel<<<dim3(NB, NA / 64), 256, 0, stream>>>(q, W1, w1q);
  score_gemm8<<<NB * NS / BM, 512, 0, stream>>>(keysb, W2b, w1q, v, scores);
  softmax_kernel<<<NB, 256, 0, stream>>>(scores, mask, out);
}

// Round 9
// 247.293 us; speedup vs baseline: 1.3173x; 1.0240x over previous
//
#include <hip/hip_runtime.h>
#include <hip/hip_bf16.h>
#include <stdint.h>

#define NB 32
#define NS 2048
#define ND 1024
#define NA 1024
#define MASK_NEG 1e30f

#define BM 256
#define BN 256
#define BK 64
#define NTILES 64  // 4 a-tiles x 16 K-tiles

typedef __attribute__((ext_vector_type(4))) float f32x4;
typedef __attribute__((ext_vector_type(8))) __bf16 bf16x8;

__device__ __forceinline__ void glds16(const void* g, void* l) {
  __builtin_amdgcn_global_load_lds(
      (const __attribute__((address_space(1))) uint32_t*)g,
      (__attribute__((address_space(3))) uint32_t*)(uintptr_t)l, 16, 0, 0);
}

// ---------------- fp32 -> bf16 bulk convert (W2 only now) ----------------
__global__ __launch_bounds__(256) void cvt_bf16(const float* __restrict__ in,
                                                __bf16* __restrict__ out, int n8) {
  long i = blockIdx.x * 256 + threadIdx.x;
  const long stride = (long)gridDim.x * 256;
  for (; i < n8; i += stride) {
    f32x4 a = ((const f32x4*)in)[2 * i];
    f32x4 b = ((const f32x4*)in)[2 * i + 1];
    bf16x8 o;
#pragma unroll
    for (int j = 0; j < 4; ++j) { o[j] = (__bf16)a[j]; o[4 + j] = (__bf16)b[j]; }
    ((bf16x8*)out)[i] = o;
  }
}

// ---------------- w1q[b,a] = query[b,:] . W1[a,:]  (fp32) ----------------
__global__ __launch_bounds__(256) void w1q_kernel(const float* __restrict__ q,
                                                  const float* __restrict__ W1,
                                                  float* __restrict__ w1q) {
  const int b = blockIdx.x;
  const int a0 = blockIdx.y * 64;
  const int t = threadIdx.x;
  const int al = t >> 2;
  const int part = t & 3;
  const float* wrow = W1 + (size_t)(a0 + al) * ND + part * 256;
  const float* qrow = q + (size_t)b * ND + part * 256;
  float sum = 0.f;
#pragma unroll 8
  for (int i = 0; i < 256; i += 4) {
    float4 w = *reinterpret_cast<const float4*>(wrow + i);
    float4 x = *reinterpret_cast<const float4*>(qrow + i);
    sum += w.x * x.x + w.y * x.y + w.z * x.z + w.w * x.w;
  }
  __shared__ float red[256];
  red[t] = sum;
  __syncthreads();
  if (t < 64) {
    w1q[(size_t)b * NA + a0 + t] = red[t * 4] + red[t * 4 + 1] + red[t * 4 + 2] + red[t * 4 + 3];
  }
}

// ---------------- fused scores GEMM: R8 schedule + fused keys cvt at nt=0 ----------------
// Schedule identical to R8 (passed, 0 conflicts): 8 phases / 2 K-tiles,
// staggered half-tile staging, counted vmcnt(2) at ph4/ph8.
// NEW: tiles 0..15 (first a-tile pass) stage A via registers from fp32 keys:
// load fp32 -> cvt -> ds_write the SAME swizzled LDS bytes glds would write,
// and ALSO store bf16 to keysb (private rows per block; read >=8 iters later
// via glds -> L2-visible, many vmcnt waits in between). Tiles >=16 restage
// from keysb with glds16 as before. Removes the standalone 67us cvt pass.
__global__ __launch_bounds__(512, 1) void score_gemm8(
    const float* __restrict__ keysf, __bf16* __restrict__ keysb,
    const __bf16* __restrict__ W2b,
    const float* __restrict__ w1q, const float* __restrict__ vvec,
    float* __restrict__ scores) {
  __shared__ __bf16 ldsA[4][128 * BK];  // [slot*2+half][...] 64 KB
  __shared__ __bf16 ldsB[4][128 * BK];  // 64 KB
  __shared__ float sm_w1q[NA];          // 4 KB
  __shared__ float sm_v[NA];            // 4 KB
  __shared__ float sm_part[4][BM];      // 4 KB

  const int t = threadIdx.x;
  const int bs0 = blockIdx.x * BM;
  const int b = bs0 >> 11;  // / NS
  const int lane = t & 63;
  const int wid = t >> 6;
  const int wr = wid >> 2;   // 0..1: 128-row half of output
  const int wc = wid & 3;    // 0..3: 64-col quarter; B-half = wc>>1
  const int lrow = lane & 15;
  const int ko = lane >> 4;

  for (int i = t; i < NA; i += 512) {
    sm_w1q[i] = w1q[(size_t)b * NA + i];
    sm_v[i] = vvec[i];
  }
  for (int i = t; i < 4 * BM; i += 512) ((float*)sm_part)[i] = 0.f;

  // staging lane geometry (R2-verified involution): 1 glds = 1 KB = 8 rows of
  // 128 B; this thread stages rows wid*16+j*8+srow (j=0,1) of each half-tile.
  const int srow = lane >> 3;
  const int scol = (lane & 7) ^ srow;
  const size_t aoffT = (size_t)(bs0 + wid * 16 + srow) * ND + scol * 8;
  const size_t boffT = (size_t)(wid * 16 + srow) * ND + scol * 8;

  // fragment read slots (pre-swizzled; row offsets are multiples of 8)
  const int sl0 = ko ^ (lrow & 7);
  const int sl1 = (4 + ko) ^ (lrow & 7);

#define STAGE_A(T, H)                                                           \
  do {                                                                          \
    if ((T) < NTILES) {                                                         \
      char* d_ = (char*)ldsA + (((((T)&1) << 1) + (H)) << 14) + wid * 2048;     \
      if ((T) < 16) { /* fused cvt pass: fp32 -> bf16 -> LDS + keysb */         \
        const size_t rb_ = (size_t)(bs0 + (H)*128 + wid * 16 + srow);           \
        const int kk_ = (T)*64 + scol * 8;                                      \
        _Pragma("unroll") for (int j = 0; j < 2; ++j) {                         \
          const float* gp_ = keysf + (rb_ + j * 8) * ND + kk_;                  \
          float4 x0_ = *reinterpret_cast<const float4*>(gp_);                   \
          float4 x1_ = *reinterpret_cast<const float4*>(gp_ + 4);               \
          bf16x8 o_;                                                            \
          o_[0] = (__bf16)x0_.x; o_[1] = (__bf16)x0_.y;                         \
          o_[2] = (__bf16)x0_.z; o_[3] = (__bf16)x0_.w;                         \
          o_[4] = (__bf16)x1_.x; o_[5] = (__bf16)x1_.y;                         \
          o_[6] = (__bf16)x1_.z; o_[7] = (__bf16)x1_.w;                         \
          *reinterpret_cast<bf16x8*>(d_ + j * 1024 + srow * 128 +               \
                                     (lane & 7) * 16) = o_;                     \
          *reinterpret_cast<bf16x8*>(keysb + (rb_ + j * 8) * ND + kk_) = o_;    \
        }                                                                       \
      } else {                                                                  \
        const size_t g_ = aoffT + (size_t)((H)*128) * ND + (size_t)(((T)&15) * BK); \
        glds16(keysb + g_, d_);                                                 \
        glds16(keysb + g_ + (size_t)8 * ND, d_ + 1024);                         \
      }                                                                         \
    }                                                                           \
  } while (0)

#define STAGE_B(T, H)                                                           \
  do {                                                                          \
    if ((T) < NTILES) {                                                         \
      char* d_ = (char*)ldsB + (((((T)&1) << 1) + (H)) << 14) + wid * 2048;     \
      const size_t g_ = boffT + (size_t)(((T) >> 4) * 256 + (H)*128) * ND +     \
                        (size_t)(((T)&15) * BK);                                \
      glds16(W2b + g_, d_);                                                     \
      glds16(W2b + g_ + (size_t)8 * ND, d_ + 1024);                             \
    }                                                                           \
  } while (0)

#define SB __builtin_amdgcn_sched_barrier(0)
#define P1 __builtin_amdgcn_s_setprio(1)
#define P0 __builtin_amdgcn_s_setprio(0)
#define BAR __builtin_amdgcn_s_barrier()

  // PHASE: 1 half-tile stage first (loads issue early), then reads (af only on
  // N_==0 phases; reused on N_==1) -> BAR -> lgkm(0) -> 16 MFMA -> [vm] -> BAR.
#define PHASE(TL, M_, N_, STAGE_STMT, WM)                                       \
  do {                                                                          \
    STAGE_STMT;                                                                 \
    if ((N_) == 0) {                                                            \
      const char* Ab_ = (const char*)ldsA + (((((TL)&1) << 1) | wr) << 14);     \
      _Pragma("unroll") for (int mi = 0; mi < 4; ++mi) {                        \
        const int ra_ = (((M_)*4 + mi) * 16 + lrow) * 128;                      \
        af[mi][0] = *reinterpret_cast<const bf16x8*>(Ab_ + ra_ + sl0 * 16);     \
        af[mi][1] = *reinterpret_cast<const bf16x8*>(Ab_ + ra_ + sl1 * 16);     \
      }                                                                         \
    }                                                                           \
    {                                                                           \
      const char* Bb_ = (const char*)ldsB + (((((TL)&1) << 1) | (wc >> 1)) << 14); \
      _Pragma("unroll") for (int nq = 0; nq < 2; ++nq) {                        \
        const int rb_ = (((wc & 1) * 4 + (N_)*2 + nq) * 16 + lrow) * 128;       \
        bfr[nq][0] = *reinterpret_cast<const bf16x8*>(Bb_ + rb_ + sl0 * 16);    \
        bfr[nq][1] = *reinterpret_cast<const bf16x8*>(Bb_ + rb_ + sl1 * 16);    \
      }                                                                         \
    }                                                                           \
    BAR;                                                                        \
    asm volatile("s_waitcnt lgkmcnt(0)");                                       \
    SB;                                                                         \
    P1;                                                                         \
    _Pragma("unroll") for (int mi = 0; mi < 4; ++mi)                            \
        _Pragma("unroll") for (int nq = 0; nq < 2; ++nq) {                      \
      acc[(M_)*4 + mi][(N_)*2 + nq] = __builtin_amdgcn_mfma_f32_16x16x32_bf16(  \
          af[mi][0], bfr[nq][0], acc[(M_)*4 + mi][(N_)*2 + nq], 0, 0, 0);       \
      acc[(M_)*4 + mi][(N_)*2 + nq] = __builtin_amdgcn_mfma_f32_16x16x32_bf16(  \
          af[mi][1], bfr[nq][1], acc[(M_)*4 + mi][(N_)*2 + nq], 0, 0, 0);       \
    }                                                                           \
    P0;                                                                         \
    if (WM) {                                                                   \
      if (it != 31) { asm volatile("s_waitcnt vmcnt(2)"); }                     \
      else { asm volatile("s_waitcnt vmcnt(0)"); }                              \
      SB;                                                                       \
    }                                                                           \
    BAR;                                                                        \
  } while (0)

  f32x4 acc[8][4];
#pragma unroll
  for (int mi = 0; mi < 8; ++mi)
#pragma unroll
    for (int ni = 0; ni < 4; ++ni) acc[mi][ni] = f32x4{0.f, 0.f, 0.f, 0.f};

  bf16x8 af[4][2], bfr[2][2];

  // ---- prologue: A(0,*), B(0,*), A(1,h0); drain once ----
  STAGE_A(0, 0);
  STAGE_A(0, 1);
  STAGE_B(0, 0);
  STAGE_B(0, 1);
  STAGE_A(1, 0);
  __syncthreads();  // drains vmcnt/lgkm; also sm_* init

  for (int it = 0; it < 32; ++it) {
    const int t0 = 2 * it, t1 = 2 * it + 1;
    PHASE(t0, 0, 0, STAGE_A(t1, 1), 0);       // ph1
    PHASE(t0, 0, 1, STAGE_B(t1, 0), 0);       // ph2
    PHASE(t0, 1, 0, STAGE_B(t1, 1), 0);       // ph3
    PHASE(t0, 1, 1, STAGE_A(t0 + 2, 0), 1);   // ph4 + vmcnt(2)
    PHASE(t1, 0, 0, STAGE_A(t0 + 2, 1), 0);   // ph5
    PHASE(t1, 0, 1, STAGE_B(t0 + 2, 0), 0);   // ph6
    PHASE(t1, 1, 0, STAGE_B(t0 + 2, 1), 0);   // ph7
    PHASE(t1, 1, 1, STAGE_A(t1 + 2, 0), 1);   // ph8 + vmcnt(2)

    // ---- per-a-tile epilogue: tanh + v-weight -> sm_part ----
    if ((it & 7) == 7) {
      const int a0 = (it >> 3) * BN;
      float w1v[4], vv[4];
#pragma unroll
      for (int ni = 0; ni < 4; ++ni) {
        const int a = a0 + wc * 64 + ni * 16 + lrow;
        w1v[ni] = sm_w1q[a];
        vv[ni] = sm_v[a];
      }
#pragma unroll
      for (int mi = 0; mi < 8; ++mi)
#pragma unroll
        for (int r = 0; r < 4; ++r) {
          float p = 0.f;
#pragma unroll
          for (int ni = 0; ni < 4; ++ni) {
            const float x = acc[mi][ni][r] + w1v[ni];
            const float e = __expf(2.f * x);
            p += (1.f - 2.f * __builtin_amdgcn_rcpf(e + 1.f)) * vv[ni];
          }
          p += __shfl_xor(p, 1);
          p += __shfl_xor(p, 2);
          p += __shfl_xor(p, 4);
          p += __shfl_xor(p, 8);
          if (lrow == 0) sm_part[wc][wr * 128 + mi * 16 + ko * 4 + r] += p;
        }
#pragma unroll
      for (int mi = 0; mi < 8; ++mi)
#pragma unroll
        for (int ni = 0; ni < 4; ++ni) acc[mi][ni] = f32x4{0.f, 0.f, 0.f, 0.f};
    }
  }

  __syncthreads();
  if (t < BM)
    scores[bs0 + t] = sm_part[0][t] + sm_part[1][t] + sm_part[2][t] + sm_part[3][t];

#undef STAGE_A
#undef STAGE_B
#undef PHASE
#undef SB
#undef P1
#undef P0
#undef BAR
}

// ---------------- masked softmax ----------------
__global__ __launch_bounds__(256) void softmax_kernel(const float* __restrict__ scores,
                                                      const int* __restrict__ mask,
                                                      float* __restrict__ out) {
  const int b = blockIdx.x;
  const int t = threadIdx.x;
  float sc[8];
  float mx = -3.4e38f;
#pragma unroll
  for (int j = 0; j < 8; ++j) {
    int i = t + j * 256;
    float s = scores[b * NS + i];
    if (mask[b * NS + i] == 0) s -= MASK_NEG;
    sc[j] = s;
    mx = fmaxf(mx, s);
  }
#pragma unroll
  for (int off = 1; off < 64; off <<= 1) mx = fmaxf(mx, __shfl_xor(mx, off));
  __shared__ float redm[4];
  __shared__ float reds[4];
  if ((t & 63) == 0) redm[t >> 6] = mx;
  __syncthreads();
  mx = fmaxf(fmaxf(redm[0], redm[1]), fmaxf(redm[2], redm[3]));
  float e[8];
  float sum = 0.f;
#pragma unroll
  for (int j = 0; j < 8; ++j) {
    e[j] = __expf(sc[j] - mx);
    sum += e[j];
  }
#pragma unroll
  for (int off = 1; off < 64; off <<= 1) sum += __shfl_xor(sum, off);
  if ((t & 63) == 0) reds[t >> 6] = sum;
  __syncthreads();
  sum = reds[0] + reds[1] + reds[2] + reds[3];
  float inv = 1.f / sum;
#pragma unroll
  for (int j = 0; j < 8; ++j) out[b * NS + t + j * 256] = e[j] * inv;
}

extern "C" void kernel_launch(void* const* d_in, const int* in_sizes, int n_in,
                              void* d_out, int out_size, void* d_ws, size_t ws_size,
                              hipStream_t stream) {
  const float* q = (const float*)d_in[0];
  const float* keysf = (const float*)d_in[1];
  const int* mask = (const int*)d_in[2];
  const float* W1 = (const float*)d_in[3];
  const float* W2f = (const float*)d_in[4];
  const float* v = (const float*)d_in[5];
  float* out = (float*)d_out;

  float* scores = (float*)d_ws;                                 // 256 KB
  float* w1q = scores + NB * NS;                                // 128 KB
  __bf16* W2b = (__bf16*)(w1q + NB * NA);                       // 2 MB
  __bf16* keysb = (__bf16*)((char*)W2b + (size_t)NA * ND * 2);  // 128 MB

  cvt_bf16<<<512, 256, 0, stream>>>(W2f, W2b, NA * ND / 8);
  w1q_kernel<<<dim3(NB, NA / 64), 256, 0, stream>>>(q, W1, w1q);
  score_gemm8<<<NB * NS / BM, 512, 0, stream>>>(keysf, keysb, W2b, w1q, v, scores);
  softmax_kernel<<<NB, 256, 0, stream>>>(scores, mask, out);
}